// Round 1
// baseline (349.182 us; speedup 1.0000x reference)
//
#include <hip/hip_runtime.h>

#define N_RAYS 262144
#define N_PTS  64
#define FAR_DELTA 1e10f
#define RAYS_PER_BLOCK 4   // 256 threads = 4 waves, 1 wave per ray

__global__ __launch_bounds__(256) void volume_render_kernel(
    const float* __restrict__ density,       // (N, 64, 1)
    const float* __restrict__ depth_values,  // (N, 64)
    const float* __restrict__ rays_feature,  // (N, 64, 3)
    float* __restrict__ out)                 // feature (N*3) then depth (N)
{
    const int wave = threadIdx.x >> 6;
    const int lane = threadIdx.x & 63;
    const int ray  = blockIdx.x * RAYS_PER_BLOCK + wave;

    const long base = (long)ray * N_PTS;

    // Coalesced loads: lane i <-> sample i (256B contiguous per instruction)
    const float d_i = depth_values[base + lane];
    const float sig = density[base + lane];

    // Feature loads issued EARLY so HBM latency hides under the scan chain.
    // Flat elements lane, lane+64, lane+128 of the ray's 192-float block:
    // each instruction reads 256 contiguous bytes (4 cache lines), vs the
    // previous stride-12 pattern (12 lines touched per instruction).
    const float* fbase = rays_feature + (long)ray * (N_PTS * 3);
    const float f0 = fbase[lane];
    const float f1 = fbase[lane + 64];
    const float f2 = fbase[lane + 128];

    // delta_i = depth[i+1] - depth[i]; last sample gets the far sentinel
    float d_next = __shfl_down(d_i, 1, 64);
    float delta  = (lane == 63) ? FAR_DELTA : (d_next - d_i);
    float sd     = sig * delta;   // sigma * delta (lane 63 may be ~1e10)

    // Inclusive prefix sum of sd across the wave (6 shuffle steps)
    float s = sd;
    #pragma unroll
    for (int off = 1; off < 64; off <<= 1) {
        float t = __shfl_up(s, off, 64);
        if (lane >= off) s += t;
    }
    // Exclusive prefix: shift inclusive up one lane. Lane 63's inclusive
    // value (contains the 1e10 sentinel) is never consumed.
    float s_exc = __shfl_up(s, 1, 64);
    if (lane == 0) s_exc = 0.0f;

    // transmittance T_i = exp(-s_exc); weight = T_i * (1 - exp(-sd_i))
    const float e = __expf(-sd);          // exp(-1e10) -> 0, fine
    const float w = __expf(-s_exc) * (1.0f - e);

    // Weight gather for the coalesced-flat feature elements.
    // Element e_k = lane + 64k -> sample e_k/3 (weight lives in that lane).
    const float p0 = f0 * __shfl(w, lane / 3, 64);
    const float p1 = f1 * __shfl(w, (lane + 64) / 3, 64);
    const float p2 = f2 * __shfl(w, (lane + 128) / 3, 64);

    // Component routing: 64 % 3 == 1, so comp(e_k) = (lane + k) % 3.
    // Each lane holds exactly one product per component.
    const int r = lane % 3;
    float fx = (r == 0) ? p0 : ((r == 1) ? p2 : p1);
    float fy = (r == 0) ? p1 : ((r == 1) ? p0 : p2);
    float fz = (r == 0) ? p2 : ((r == 1) ? p1 : p0);
    float wd = w * d_i;

    // Butterfly reduce all four accumulators across the wave.
    // (xor-butterfly leaves the full sum in EVERY lane.)
    #pragma unroll
    for (int off = 32; off > 0; off >>= 1) {
        fx += __shfl_xor(fx, off, 64);
        fy += __shfl_xor(fy, off, 64);
        fz += __shfl_xor(fz, off, 64);
        wd += __shfl_xor(wd, off, 64);
    }

    // Spread the epilogue store across lanes 0..3: one store instruction
    // with 4 active lanes instead of 4 scalar stores from lane 0.
    if (lane < 3) {
        const float v = (lane == 0) ? fx : ((lane == 1) ? fy : fz);
        out[(long)ray * 3 + lane] = v;
    } else if (lane == 3) {
        out[(long)N_RAYS * 3 + ray] = wd;
    }
}

extern "C" void kernel_launch(void* const* d_in, const int* in_sizes, int n_in,
                              void* d_out, int out_size, void* d_ws, size_t ws_size,
                              hipStream_t stream) {
    const float* density      = (const float*)d_in[0];
    const float* depth_values = (const float*)d_in[1];
    const float* rays_feature = (const float*)d_in[2];
    float* out = (float*)d_out;

    const int blocks = N_RAYS / RAYS_PER_BLOCK;  // 65536
    volume_render_kernel<<<blocks, 256, 0, stream>>>(
        density, depth_values, rays_feature, out);
}